// Round 13
// baseline (5248.503 us; speedup 1.0000x reference)
//
#include <hip/hip_runtime.h>

typedef unsigned int u32;
typedef unsigned long long u64;

#define Bc 256
#define Tc 325
#define NSc 39
#define COc 64
#define NCc 20
#define ESc 117
#define ETc 648

// workspace layout in 4-byte units
#define WS_ROFF_S 0        // 40 ints
#define WS_EDGE_S 64       // 117 int2
#define WS_DINV_S 304      // 39 f
#define WS_ROFF_T 352      // 326 ints
#define WS_EDGE_T 680      // 648 int2
#define WS_DINV_T 1976     // 325 f
#define WS_W1T    2304     // 49920 f  (fc1_w transposed [20][2496])
#define WS_W2T    52224    // 416000 f (tfc1_w transposed [20][20800])

// ---------------- prep: CSR (by dst, interleaved {src, nrm}) ----------------
__global__ void prep_graph(const int* __restrict__ eiS, const int* __restrict__ eiT,
                           int* __restrict__ wsI, float* __restrict__ wsF) {
  const int which = blockIdx.x;
  const int* ei = which ? eiT : eiS;
  const int nE = which ? ETc : ESc;
  const int nN = which ? Tc : NSc;
  int* roff = wsI + (which ? WS_ROFF_T : WS_ROFF_S);
  int2* edge = (int2*)(wsI + (which ? WS_EDGE_T : WS_EDGE_S));
  float* dinv = wsF + (which ? WS_DINV_T : WS_DINV_S);
  const int* src = ei;
  const int* dst = ei + nE;
  for (int n = threadIdx.x; n < nN; n += blockDim.x) {
    int deg = 0, before = 0;
    for (int e = 0; e < nE; ++e) { deg += (dst[e] == n); before += (dst[e] < n); }
    roff[n] = before;
    if (n == nN - 1) roff[nN] = before + deg;
    dinv[n] = (deg > 0) ? (1.0f / sqrtf((float)deg)) : 0.0f;
  }
  __syncthreads();
  for (int n = threadIdx.x; n < nN; n += blockDim.x) {
    int cur = roff[n];
    float dn = dinv[n];
    for (int e = 0; e < nE; ++e) {
      if (dst[e] == n) {
        edge[cur] = make_int2(src[e], __float_as_int(dinv[src[e]] * dn));
        ++cur;
      }
    }
  }
}

// ---------------- prep: transpose both fc weights ----------------
__global__ void prep_w(const float* __restrict__ w1, float* __restrict__ w1T,
                       const float* __restrict__ w2, float* __restrict__ w2T) {
  int i = blockIdx.x * 256 + threadIdx.x;
  if (i < NCc * Tc * COc) {
    int j = i / (Tc * COc);
    int p = i - j * (Tc * COc);
    w2T[i] = w2[p * NCc + j];
  }
  if (i < NCc * NSc * COc) {
    int j = i / (NSc * COc);
    int p = i - j * (NSc * COc);
    w1T[i] = w1[p * NCc + j];
  }
}

// ---------------- fused kernel: 1 batch per block, 1024 threads (16 waves), <=64 VGPR design ----------------
__global__ __launch_bounds__(1024)
void lif_fused(const float* __restrict__ data,
               const int* __restrict__ roffSg, const int2* __restrict__ edgeSg,
               const int* __restrict__ roffTg, const int2* __restrict__ edgeTg,
               const float* __restrict__ c1w, const float* __restrict__ c1b,
               const float* __restrict__ c2w, const float* __restrict__ c2b,
               const float* __restrict__ w1T, const float* __restrict__ f1b,
               const float* __restrict__ w2T, const float* __restrict__ tf1b,
               float* __restrict__ out)
{
  __shared__ u64 spk[NSc * Tc];                  // 101400 B: A=[t][39], B=[s][325]
  __shared__ __align__(16) float fAB[9984];      // A: [16][39][16] / B: [16][328]
  __shared__ float partials[624];                // [8jg][2ih][13ds][3jj]
  __shared__ float cwL[1024];
  __shared__ float outS_l[NCc];
  __shared__ int roffS[NSc + 1];
  __shared__ int2 edgeS[ESc];
  __shared__ int roffT[Tc + 1];
  __shared__ int2 edgeT[ETc];

  const int tid = threadIdx.x;
  const int lane = tid & 63;
  const int wv = tid >> 6;             // 0..15
  const int b = blockIdx.x;
  const int lhalf = lane >> 5;
  const int lbit = lane & 31;
  const float* dbase = data + (size_t)b * (2 * NSc * 2 * Tc);

  for (int i = tid; i < NSc + 1; i += 1024) roffS[i] = roffSg[i];
  for (int i = tid; i < ESc; i += 1024) edgeS[i] = edgeSg[i];
  for (int i = tid; i < Tc + 1; i += 1024) roffT[i] = roffTg[i];
  for (int i = tid; i < ETc; i += 1024) edgeT[i] = edgeTg[i];
  for (int i = tid; i < 1024; i += 1024) cwL[i] = c1w[i];

  // fc decomposition: 8 j-groups (4x3j + 4x2j) x 2 i-halves
  const int jg = wv >> 1, ih = wv & 1;
  const int j0 = (jg < 4) ? jg * 3 : 12 + (jg - 4) * 2;
  const int jn = (jg < 4) ? 3 : 2;
  // owned outputs for h-LIF: ja = wv (0..15), jb = 16+wv (wv<4)
  const int ja = wv;
  const int jag = (ja < 12) ? ja / 3 : 4 + (ja - 12) / 2;
  const int jaj = (ja < 12) ? ja % 3 : (ja - 12) % 2;
  const int jb = 16 + wv;
  const int jbg = 4 + (jb - 12) / 2;
  const int jbj = (jb - 12) % 2;

  // ============ Phase A: spatial, per 13-t chunk ============
  {
    const float bcv = c1b[lane];
    float cm[3] = {0, 0, 0};
    const int nq = (wv < 7) ? 3 : 2;
    const int iBase = ih * 20, iN = ih ? 19 : 20;
    const float* wq0 = w1T + (j0 + 0) * (NSc * COc) + iBase * COc + lane;
    const float* wq1 = w1T + (j0 + 1) * (NSc * COc) + iBase * COc + lane;
    const float* wq2 = w1T + ((jn > 2) ? j0 + 2 : j0) * (NSc * COc) + iBase * COc + lane;
    const float ba = f1b[ja];
    const float bb = (wv < 4) ? f1b[jb] : 0.0f;
    float hma = 0, hsa = 0, hmb = 0, hsb = 0;
    __syncthreads();

#pragma unroll 1
    for (int ch = 0; ch < 25; ++ch) {
      const int t0 = ch * 13;
      // stage x: fA[c][n][dt16]
#pragma unroll
      for (int it = 0; it < 3; ++it) {
        int idx = tid + it * 1024;
        if (idx < 2496) {
          int n = idx >> 6, c = (idx >> 4) & 3, dt = idx & 15;
          float v = 0.0f;
          if (dt < 13) v = dbase[(n + (c >> 1) * NSc) * 650 + (c & 1) * 325 + t0 + dt];
          fAB[c * 624 + n * 16 + dt] = v;
        }
      }
      __syncthreads();
      // 3 hops
#pragma unroll
      for (int k = 1; k <= 3; ++k) {
#pragma unroll
        for (int it = 0; it < 3; ++it) {
          int idx = tid + it * 1024;
          if (idx < 2496) {
            int n = idx >> 6, c = (idx >> 4) & 3, dt = idx & 15;
            float v = 0.0f;
            for (int e = roffS[n]; e < roffS[n + 1]; ++e) {
              int2 ed = edgeS[e];
              v = fmaf(__int_as_float(ed.y), fAB[((k - 1) * 4 + c) * 624 + ed.x * 16 + dt], v);
            }
            fAB[(k * 4 + c) * 624 + n * 16 + dt] = v;
          }
        }
        __syncthreads();
      }
      // conv + LIF + ballot -> spk[t][i]
      {
        float wcr[16];
#pragma unroll
        for (int r = 0; r < 16; ++r) wcr[r] = cwL[r * 64 + lane];
#pragma unroll
        for (int q = 0; q < 3; ++q) {
          if (q < nq) {
            int i = wv + 16 * q;
            float za[13];
#pragma unroll
            for (int dt = 0; dt < 13; ++dt) za[dt] = bcv;
#pragma unroll
            for (int r = 0; r < 16; ++r) {
              const float* fp = &fAB[r * 624 + i * 16];
              float w = wcr[r];
              float4 a0 = *(const float4*)fp;
              float4 a1 = *(const float4*)(fp + 4);
              float4 a2 = *(const float4*)(fp + 8);
              float a3 = fp[12];
              za[0] = fmaf(a0.x, w, za[0]);   za[1] = fmaf(a0.y, w, za[1]);
              za[2] = fmaf(a0.z, w, za[2]);   za[3] = fmaf(a0.w, w, za[3]);
              za[4] = fmaf(a1.x, w, za[4]);   za[5] = fmaf(a1.y, w, za[5]);
              za[6] = fmaf(a1.z, w, za[6]);   za[7] = fmaf(a1.w, w, za[7]);
              za[8] = fmaf(a2.x, w, za[8]);   za[9] = fmaf(a2.y, w, za[9]);
              za[10] = fmaf(a2.z, w, za[10]); za[11] = fmaf(a2.w, w, za[11]);
              za[12] = fmaf(a3, w, za[12]);
            }
#pragma unroll
            for (int dt = 0; dt < 13; ++dt) {
              float old = cm[q];
              float m = (old * 0.2f) * ((old > 0.5f) ? 0.0f : 1.0f) + za[dt];
              cm[q] = m;
              u64 wd = __ballot(m > 0.5f);
              if (lane == 0) spk[(t0 + dt) * NSc + i] = wd;
            }
          }
        }
      }
      __syncthreads();
      // fc GEMM over chunk: ya[13][3]
      float ya[13][3];
#pragma unroll
      for (int ds = 0; ds < 13; ++ds) {
        ya[ds][0] = 0.0f; ya[ds][1] = 0.0f; ya[ds][2] = 0.0f;
      }
#pragma unroll 1
      for (int ii = 0; ii < iN; ++ii) {
        const int i = iBase + ii;
        float w0 = wq0[ii * COc];
        float w1 = wq1[ii * COc];
        float w2 = wq2[ii * COc];
#pragma unroll
        for (int ds = 0; ds < 13; ++ds) {
          u32 wrd = ((const u32*)spk)[((t0 + ds) * NSc + i) * 2 + lhalf];
          float g = (float)((wrd >> lbit) & 1u);
          ya[ds][0] = fmaf(g, w0, ya[ds][0]);
          ya[ds][1] = fmaf(g, w1, ya[ds][1]);
          ya[ds][2] = fmaf(g, w2, ya[ds][2]);
        }
      }
#pragma unroll
      for (int off = 32; off >= 1; off >>= 1)
#pragma unroll
        for (int ds = 0; ds < 13; ++ds) {
          ya[ds][0] += __shfl_xor(ya[ds][0], off, 64);
          ya[ds][1] += __shfl_xor(ya[ds][1], off, 64);
          ya[ds][2] += __shfl_xor(ya[ds][2], off, 64);
        }
      if (lane == 0) {
#pragma unroll
        for (int ds = 0; ds < 13; ++ds) {
          partials[((jg * 2 + ih) * 13 + ds) * 3 + 0] = ya[ds][0];
          partials[((jg * 2 + ih) * 13 + ds) * 3 + 1] = ya[ds][1];
          partials[((jg * 2 + ih) * 13 + ds) * 3 + 2] = ya[ds][2];
        }
      }
      __syncthreads();
      // h-LIF for owned outputs
#pragma unroll
      for (int ds = 0; ds < 13; ++ds) {
        float y0 = partials[((jag * 2 + 0) * 13 + ds) * 3 + jaj]
                 + partials[((jag * 2 + 1) * 13 + ds) * 3 + jaj] + ba;
        hma = (hma * 0.2f) * ((hma > 0.5f) ? 0.0f : 1.0f) + y0;
        hsa += (hma > 0.5f) ? 1.0f : 0.0f;
        if (wv < 4) {
          float y1 = partials[((jbg * 2 + 0) * 13 + ds) * 3 + jbj]
                   + partials[((jbg * 2 + 1) * 13 + ds) * 3 + jbj] + bb;
          hmb = (hmb * 0.2f) * ((hmb > 0.5f) ? 0.0f : 1.0f) + y1;
          hsb += (hmb > 0.5f) ? 1.0f : 0.0f;
        }
      }
      __syncthreads();
    }
    if (lane == 0) {
      outS_l[ja] = hsa / (float)Tc;
      if (wv < 4) outS_l[jb] = hsb / (float)Tc;
    }
  }
  __syncthreads();

  // ============ Phase B1: temporal conv chain -> spk[s][i] ============
  {
    float wc[16];
#pragma unroll
    for (int r = 0; r < 16; ++r) wc[r] = c2w[r * COc + lane];
    const float bcv = c2b[lane];
    float tm[21];
#pragma unroll
    for (int q = 0; q < 21; ++q) tm[q] = 0.0f;
    const int nq = (wv < 5) ? 21 : 20;

#pragma unroll 1
    for (int s = 0; s < NSc; ++s) {
#pragma unroll
      for (int it = 0; it < 2; ++it) {
        int idx = tid + it * 1024;
        if (idx < Tc * 4) {
          int c = idx / Tc, t = idx - c * Tc;
          fAB[c * 328 + t] = dbase[(s + (c >> 1) * NSc) * 650 + (c & 1) * 325 + t];
        }
      }
      __syncthreads();
#pragma unroll
      for (int k = 1; k <= 3; ++k) {
#pragma unroll
        for (int it = 0; it < 2; ++it) {
          int idx = tid + it * 1024;
          if (idx < Tc * 4) {
            int c = idx / Tc, t = idx - c * Tc;
            float v = 0.0f;
            for (int e = roffT[t]; e < roffT[t + 1]; ++e) {
              int2 ed = edgeT[e];
              v = fmaf(__int_as_float(ed.y), fAB[((k - 1) * 4 + c) * 328 + ed.x], v);
            }
            fAB[(k * 4 + c) * 328 + t] = v;
          }
        }
        __syncthreads();
      }
#pragma unroll
      for (int q = 0; q < 21; ++q) {
        if (q < nq) {
          int i = wv + 16 * q;
          float acc = bcv;
#pragma unroll
          for (int r = 0; r < 16; ++r) acc = fmaf(fAB[r * 328 + i], wc[r], acc);
          float old = tm[q];
          float m = (old * 0.2f) * ((old > 0.5f) ? 0.0f : 1.0f) + acc;
          tm[q] = m;
          u64 wd = __ballot(m > 0.5f);
          if (lane == 0) spk[s * Tc + i] = wd;
        }
      }
      __syncthreads();
    }
  }

  // ============ Phase B2: temporal fc binary GEMM + h-LIF + combine ============
  {
    const int iBase = ih * 163, iN = ih ? 162 : 163;
    const float* wq0 = w2T + (size_t)(j0 + 0) * (Tc * COc) + iBase * COc + lane;
    const float* wq1 = w2T + (size_t)(j0 + 1) * (Tc * COc) + iBase * COc + lane;
    const float* wq2 = w2T + (size_t)((jn > 2) ? j0 + 2 : j0) * (Tc * COc) + iBase * COc + lane;
    const float ba = tf1b[ja];
    const float bb = (wv < 4) ? tf1b[jb] : 0.0f;
    float hma = 0, hsa = 0, hmb = 0, hsb = 0;

#pragma unroll 1
    for (int chn = 0; chn < 3; ++chn) {
      const int s0 = chn * 13;
      float ya[13][3];
#pragma unroll
      for (int ds = 0; ds < 13; ++ds) {
        ya[ds][0] = 0.0f; ya[ds][1] = 0.0f; ya[ds][2] = 0.0f;
      }
#pragma unroll 1
      for (int ii = 0; ii < iN; ++ii) {
        const int i = iBase + ii;
        float w0 = wq0[(size_t)ii * COc];
        float w1 = wq1[(size_t)ii * COc];
        float w2 = wq2[(size_t)ii * COc];
#pragma unroll
        for (int ds = 0; ds < 13; ++ds) {
          u32 wrd = ((const u32*)spk)[((s0 + ds) * Tc + i) * 2 + lhalf];
          float g = (float)((wrd >> lbit) & 1u);
          ya[ds][0] = fmaf(g, w0, ya[ds][0]);
          ya[ds][1] = fmaf(g, w1, ya[ds][1]);
          ya[ds][2] = fmaf(g, w2, ya[ds][2]);
        }
      }
#pragma unroll
      for (int off = 32; off >= 1; off >>= 1)
#pragma unroll
        for (int ds = 0; ds < 13; ++ds) {
          ya[ds][0] += __shfl_xor(ya[ds][0], off, 64);
          ya[ds][1] += __shfl_xor(ya[ds][1], off, 64);
          ya[ds][2] += __shfl_xor(ya[ds][2], off, 64);
        }
      if (lane == 0) {
#pragma unroll
        for (int ds = 0; ds < 13; ++ds) {
          partials[((jg * 2 + ih) * 13 + ds) * 3 + 0] = ya[ds][0];
          partials[((jg * 2 + ih) * 13 + ds) * 3 + 1] = ya[ds][1];
          partials[((jg * 2 + ih) * 13 + ds) * 3 + 2] = ya[ds][2];
        }
      }
      __syncthreads();
#pragma unroll
      for (int ds = 0; ds < 13; ++ds) {
        float y0 = partials[((jag * 2 + 0) * 13 + ds) * 3 + jaj]
                 + partials[((jag * 2 + 1) * 13 + ds) * 3 + jaj] + ba;
        hma = (hma * 0.2f) * ((hma > 0.5f) ? 0.0f : 1.0f) + y0;
        hsa += (hma > 0.5f) ? 1.0f : 0.0f;
        if (wv < 4) {
          float y1 = partials[((jbg * 2 + 0) * 13 + ds) * 3 + jbj]
                   + partials[((jbg * 2 + 1) * 13 + ds) * 3 + jbj] + bb;
          hmb = (hmb * 0.2f) * ((hmb > 0.5f) ? 0.0f : 1.0f) + y1;
          hsb += (hmb > 0.5f) ? 1.0f : 0.0f;
        }
      }
      __syncthreads();
    }
    if (lane == 0) {
      out[b * NCc + ja] = (outS_l[ja] + hsa / (float)NSc) * 0.5f;
      if (wv < 4)
        out[b * NCc + jb] = (outS_l[jb] + hsb / (float)NSc) * 0.5f;
    }
  }
}

extern "C" void kernel_launch(void* const* d_in, const int* in_sizes, int n_in,
                              void* d_out, int out_size, void* d_ws, size_t ws_size,
                              hipStream_t stream) {
  const float* data = (const float*)d_in[0];
  const int*   eiS  = (const int*)d_in[1];
  const int*   eiT  = (const int*)d_in[2];
  const float* c1w  = (const float*)d_in[3];
  const float* c1b  = (const float*)d_in[4];
  const float* c2w  = (const float*)d_in[5];
  const float* c2b  = (const float*)d_in[6];
  const float* f1w  = (const float*)d_in[7];
  const float* f1b  = (const float*)d_in[8];
  const float* tf1w = (const float*)d_in[9];
  const float* tf1b = (const float*)d_in[10];
  float* out = (float*)d_out;
  int* wsI = (int*)d_ws;
  float* wsF = (float*)d_ws;

  prep_graph<<<2, 256, 0, stream>>>(eiS, eiT, wsI, wsF);
  prep_w<<<(NCc * Tc * COc + 255) / 256, 256, 0, stream>>>(f1w, wsF + WS_W1T,
                                                           tf1w, wsF + WS_W2T);
  lif_fused<<<Bc, 1024, 0, stream>>>(data,
                                     wsI + WS_ROFF_S, (const int2*)(wsI + WS_EDGE_S),
                                     wsI + WS_ROFF_T, (const int2*)(wsI + WS_EDGE_T),
                                     c1w, c1b, c2w, c2b,
                                     wsF + WS_W1T, f1b, wsF + WS_W2T, tf1b,
                                     out);
}

// Round 14
// 1429.903 us; speedup vs baseline: 3.6705x; 3.6705x over previous
//
#include <hip/hip_runtime.h>

typedef unsigned int u32;
typedef unsigned long long u64;

#define Bc 256
#define Tc 325
#define NSc 39
#define COc 64
#define NCc 20
#define ESc 117
#define ETc 648

// workspace layout in 4-byte units
#define WS_ROFF_S 0        // 40 ints
#define WS_EDGE_S 64       // 117 int2
#define WS_DINV_S 304      // 39 f
#define WS_ROFF_T 352      // 326 ints
#define WS_EDGE_T 680      // 648 int2
#define WS_DINV_T 1976     // 325 f
#define WS_W1T    2304     // 49920 f  (fc1_w transposed [20][2496])
#define WS_W2T    52224    // 416000 f (tfc1_w transposed [20][20800])

// ---------------- prep: CSR (by dst, interleaved {src, nrm}) ----------------
__global__ void prep_graph(const int* __restrict__ eiS, const int* __restrict__ eiT,
                           int* __restrict__ wsI, float* __restrict__ wsF) {
  const int which = blockIdx.x;
  const int* ei = which ? eiT : eiS;
  const int nE = which ? ETc : ESc;
  const int nN = which ? Tc : NSc;
  int* roff = wsI + (which ? WS_ROFF_T : WS_ROFF_S);
  int2* edge = (int2*)(wsI + (which ? WS_EDGE_T : WS_EDGE_S));
  float* dinv = wsF + (which ? WS_DINV_T : WS_DINV_S);
  const int* src = ei;
  const int* dst = ei + nE;
  for (int n = threadIdx.x; n < nN; n += blockDim.x) {
    int deg = 0, before = 0;
    for (int e = 0; e < nE; ++e) { deg += (dst[e] == n); before += (dst[e] < n); }
    roff[n] = before;
    if (n == nN - 1) roff[nN] = before + deg;
    dinv[n] = (deg > 0) ? (1.0f / sqrtf((float)deg)) : 0.0f;
  }
  __syncthreads();
  for (int n = threadIdx.x; n < nN; n += blockDim.x) {
    int cur = roff[n];
    float dn = dinv[n];
    for (int e = 0; e < nE; ++e) {
      if (dst[e] == n) {
        edge[cur] = make_int2(src[e], __float_as_int(dinv[src[e]] * dn));
        ++cur;
      }
    }
  }
}

// ---------------- prep: transpose both fc weights ----------------
__global__ void prep_w(const float* __restrict__ w1, float* __restrict__ w1T,
                       const float* __restrict__ w2, float* __restrict__ w2T) {
  int i = blockIdx.x * 256 + threadIdx.x;
  if (i < NCc * Tc * COc) {
    int j = i / (Tc * COc);
    int p = i - j * (Tc * COc);
    w2T[i] = w2[p * NCc + j];
  }
  if (i < NCc * NSc * COc) {
    int j = i / (NSc * COc);
    int p = i - j * (NSc * COc);
    w1T[i] = w1[p * NCc + j];
  }
}

// ---------------- fused kernel: 1 batch per block, 512 threads ----------------
__global__ __launch_bounds__(512) __attribute__((amdgpu_waves_per_eu(2, 2)))
void lif_fused(const float* __restrict__ data,
               const int* __restrict__ roffSg, const int2* __restrict__ edgeSg,
               const int* __restrict__ roffTg, const int2* __restrict__ edgeTg,
               const float* __restrict__ c1w, const float* __restrict__ c1b,
               const float* __restrict__ c2w, const float* __restrict__ c2b,
               const float* __restrict__ w1T, const float* __restrict__ f1b,
               const float* __restrict__ w2T, const float* __restrict__ tf1b,
               float* __restrict__ out)
{
  __shared__ u64 spk[NSc * Tc];                  // 101400 B: A=[t][39], B=[s][325]
  __shared__ __align__(16) float fAB[9984];      // A: [16][39][16] / B: [325][20] t-major
  __shared__ float partials[520];
  __shared__ float cwL[1024];
  __shared__ float outS_l[NCc];
  __shared__ int roffS[NSc + 1];
  __shared__ int2 edgeS[ESc];
  __shared__ int roffT[Tc + 1];
  __shared__ int2 edgeT[ETc];

  const int tid = threadIdx.x;
  const int lane = tid & 63;
  const int wv = tid >> 6;             // 0..7
  const int b = blockIdx.x;
  const int lhalf = lane >> 5;
  const int lbit = lane & 31;
  const float* dbase = data + (size_t)b * (2 * NSc * 2 * Tc);

  for (int i = tid; i < NSc + 1; i += 512) roffS[i] = roffSg[i];
  for (int i = tid; i < ESc; i += 512) edgeS[i] = edgeSg[i];
  for (int i = tid; i < Tc + 1; i += 512) roffT[i] = roffTg[i];
  for (int i = tid; i < ETc; i += 512) edgeT[i] = edgeTg[i];
  for (int i = tid; i < 1024; i += 512) cwL[i] = c1w[i];

  // common decomposition for fc GEMM + owned LIF outputs
  const int jg = wv >> 1, ih = wv & 1;
  const int ja = wv, jb = wv + 8, jc = wv + 16;
  const int jag = ja / 5, jaj = ja % 5;
  const int jbg = jb / 5, jbj = jb % 5;
  const int jcg = jc / 5, jcj = jc % 5;

  // ============ Phase A: spatial, per 13-t chunk: {stage, hops, conv+LIF, fc GEMM, h-LIF} ============
  {
    const float bcv = c1b[lane];
    float cm[5] = {0, 0, 0, 0, 0};
    const int iBase = ih * 20, iN = ih ? 19 : 20;
    const float* wq0 = w1T + (jg * 5 + 0) * (NSc * COc) + iBase * COc + lane;
    const float* wq1 = w1T + (jg * 5 + 1) * (NSc * COc) + iBase * COc + lane;
    const float* wq2 = w1T + (jg * 5 + 2) * (NSc * COc) + iBase * COc + lane;
    const float* wq3 = w1T + (jg * 5 + 3) * (NSc * COc) + iBase * COc + lane;
    const float* wq4 = w1T + (jg * 5 + 4) * (NSc * COc) + iBase * COc + lane;
    const float ba = f1b[ja], bb = f1b[jb];
    const float bc2 = (wv < 4) ? f1b[jc] : 0.0f;
    float hma = 0, hsa = 0, hmb = 0, hsb = 0, hmc = 0, hsc = 0;
    __syncthreads();

#pragma unroll 1
    for (int ch = 0; ch < 25; ++ch) {
      const int t0 = ch * 13;
      // stage x: fA[c][n][dt16]
#pragma unroll
      for (int it = 0; it < 5; ++it) {
        int idx = tid + it * 512;
        if (idx < 2496) {
          int n = idx >> 6, c = (idx >> 4) & 3, dt = idx & 15;
          float v = 0.0f;
          if (dt < 13) v = dbase[(n + (c >> 1) * NSc) * 650 + (c & 1) * 325 + t0 + dt];
          fAB[c * 624 + n * 16 + dt] = v;
        }
      }
      __syncthreads();
      // 3 hops
#pragma unroll
      for (int k = 1; k <= 3; ++k) {
#pragma unroll
        for (int it = 0; it < 5; ++it) {
          int idx = tid + it * 512;
          if (idx < 2496) {
            int n = idx >> 6, c = (idx >> 4) & 3, dt = idx & 15;
            float v = 0.0f;
            for (int e = roffS[n]; e < roffS[n + 1]; ++e) {
              int2 ed = edgeS[e];
              v = fmaf(__int_as_float(ed.y), fAB[((k - 1) * 4 + c) * 624 + ed.x * 16 + dt], v);
            }
            fAB[(k * 4 + c) * 624 + n * 16 + dt] = v;
          }
        }
        __syncthreads();
      }
      // conv + LIF + ballot -> spk[t][i]
      {
        float wcr[16];
#pragma unroll
        for (int r = 0; r < 16; ++r) wcr[r] = cwL[r * 64 + lane];
#pragma unroll
        for (int q = 0; q < 5; ++q) {
          int i = wv + 8 * q;
          if (i < NSc) {
            float za[13];
#pragma unroll
            for (int dt = 0; dt < 13; ++dt) za[dt] = bcv;
#pragma unroll
            for (int r = 0; r < 16; ++r) {
              const float* fp = &fAB[r * 624 + i * 16];
              float w = wcr[r];
              float4 a0 = *(const float4*)fp;
              float4 a1 = *(const float4*)(fp + 4);
              float4 a2 = *(const float4*)(fp + 8);
              float a3 = fp[12];
              za[0] = fmaf(a0.x, w, za[0]);   za[1] = fmaf(a0.y, w, za[1]);
              za[2] = fmaf(a0.z, w, za[2]);   za[3] = fmaf(a0.w, w, za[3]);
              za[4] = fmaf(a1.x, w, za[4]);   za[5] = fmaf(a1.y, w, za[5]);
              za[6] = fmaf(a1.z, w, za[6]);   za[7] = fmaf(a1.w, w, za[7]);
              za[8] = fmaf(a2.x, w, za[8]);   za[9] = fmaf(a2.y, w, za[9]);
              za[10] = fmaf(a2.z, w, za[10]); za[11] = fmaf(a2.w, w, za[11]);
              za[12] = fmaf(a3, w, za[12]);
            }
#pragma unroll
            for (int dt = 0; dt < 13; ++dt) {
              float old = cm[q];
              float m = (old * 0.2f) * ((old > 0.5f) ? 0.0f : 1.0f) + za[dt];
              cm[q] = m;
              u64 wd = __ballot(m > 0.5f);
              if (lane == 0) spk[(t0 + dt) * NSc + i] = wd;
            }
          }
        }
      }
      __syncthreads();
      // fc GEMM over chunk
      float ya[13][5];
#pragma unroll
      for (int ds = 0; ds < 13; ++ds)
#pragma unroll
        for (int jj = 0; jj < 5; ++jj) ya[ds][jj] = 0.0f;
#pragma unroll 1
      for (int ii = 0; ii < iN; ++ii) {
        const int i = iBase + ii;
        float w0 = wq0[ii * COc];
        float w1 = wq1[ii * COc];
        float w2 = wq2[ii * COc];
        float w3 = wq3[ii * COc];
        float w4 = wq4[ii * COc];
#pragma unroll
        for (int ds = 0; ds < 13; ++ds) {
          u32 wrd = ((const u32*)spk)[((t0 + ds) * NSc + i) * 2 + lhalf];
          float g = (float)((wrd >> lbit) & 1u);
          ya[ds][0] = fmaf(g, w0, ya[ds][0]);
          ya[ds][1] = fmaf(g, w1, ya[ds][1]);
          ya[ds][2] = fmaf(g, w2, ya[ds][2]);
          ya[ds][3] = fmaf(g, w3, ya[ds][3]);
          ya[ds][4] = fmaf(g, w4, ya[ds][4]);
        }
      }
#pragma unroll
      for (int off = 32; off >= 1; off >>= 1)
#pragma unroll
        for (int ds = 0; ds < 13; ++ds)
#pragma unroll
          for (int jj = 0; jj < 5; ++jj)
            ya[ds][jj] += __shfl_xor(ya[ds][jj], off, 64);
      if (lane == 0) {
#pragma unroll
        for (int ds = 0; ds < 13; ++ds)
#pragma unroll
          for (int jj = 0; jj < 5; ++jj)
            partials[(jg * 2 + ih) * 65 + ds * 5 + jj] = ya[ds][jj];
      }
      __syncthreads();
      // h-LIF for owned outputs
#pragma unroll
      for (int ds = 0; ds < 13; ++ds) {
        float y0 = partials[(jag * 2 + 0) * 65 + ds * 5 + jaj]
                 + partials[(jag * 2 + 1) * 65 + ds * 5 + jaj] + ba;
        hma = (hma * 0.2f) * ((hma > 0.5f) ? 0.0f : 1.0f) + y0;
        hsa += (hma > 0.5f) ? 1.0f : 0.0f;
        float y1 = partials[(jbg * 2 + 0) * 65 + ds * 5 + jbj]
                 + partials[(jbg * 2 + 1) * 65 + ds * 5 + jbj] + bb;
        hmb = (hmb * 0.2f) * ((hmb > 0.5f) ? 0.0f : 1.0f) + y1;
        hsb += (hmb > 0.5f) ? 1.0f : 0.0f;
        if (wv < 4) {
          float y2 = partials[(jcg * 2 + 0) * 65 + ds * 5 + jcj]
                   + partials[(jcg * 2 + 1) * 65 + ds * 5 + jcj] + bc2;
          hmc = (hmc * 0.2f) * ((hmc > 0.5f) ? 0.0f : 1.0f) + y2;
          hsc += (hmc > 0.5f) ? 1.0f : 0.0f;
        }
      }
      __syncthreads();
    }
    if (lane == 0) {
      outS_l[ja] = hsa / (float)Tc;
      outS_l[jb] = hsb / (float)Tc;
      if (wv < 4) outS_l[jc] = hsc / (float)Tc;
    }
  }
  __syncthreads();

  // ============ Phase B1: temporal conv chain -> spk[s][i], t-major [t][20] layout ============
  {
    float wc[16];
#pragma unroll
    for (int r = 0; r < 16; ++r) wc[r] = c2w[r * COc + lane];
    const float bcv = c2b[lane];
    float tm[41];
#pragma unroll
    for (int q = 0; q < 41; ++q) tm[q] = 0.0f;

#pragma unroll 1
    for (int s = 0; s < NSc; ++s) {
      // stage x_s: fAB[t*20 + c]
#pragma unroll
      for (int it = 0; it < 3; ++it) {
        int idx = tid + it * 512;
        if (idx < Tc * 4) {
          int c = idx / Tc, t = idx - c * Tc;
          fAB[t * 20 + c] = dbase[(s + (c >> 1) * NSc) * 650 + (c & 1) * 325 + t];
        }
      }
      __syncthreads();
#pragma unroll
      for (int k = 1; k <= 3; ++k) {
#pragma unroll
        for (int it = 0; it < 3; ++it) {
          int idx = tid + it * 512;
          if (idx < Tc * 4) {
            int t = idx >> 2, c = idx & 3;
            float v = 0.0f;
            for (int e = roffT[t]; e < roffT[t + 1]; ++e) {
              int2 ed = edgeT[e];
              v = fmaf(__int_as_float(ed.y), fAB[ed.x * 20 + (k - 1) * 4 + c], v);
            }
            fAB[t * 20 + k * 4 + c] = v;
          }
        }
        __syncthreads();
      }
      // conv + LIF + ballot: vectorized b128 reads from [i][20]
#pragma unroll
      for (int q = 0; q < 41; ++q) {
        int i = wv + 8 * q;
        if (i < Tc) {
          const float4* f4 = (const float4*)&fAB[i * 20];
          float4 f0 = f4[0], f1 = f4[1], f2 = f4[2], f3 = f4[3];
          float acc = bcv;
          acc = fmaf(f0.x, wc[0], acc);  acc = fmaf(f0.y, wc[1], acc);
          acc = fmaf(f0.z, wc[2], acc);  acc = fmaf(f0.w, wc[3], acc);
          acc = fmaf(f1.x, wc[4], acc);  acc = fmaf(f1.y, wc[5], acc);
          acc = fmaf(f1.z, wc[6], acc);  acc = fmaf(f1.w, wc[7], acc);
          acc = fmaf(f2.x, wc[8], acc);  acc = fmaf(f2.y, wc[9], acc);
          acc = fmaf(f2.z, wc[10], acc); acc = fmaf(f2.w, wc[11], acc);
          acc = fmaf(f3.x, wc[12], acc); acc = fmaf(f3.y, wc[13], acc);
          acc = fmaf(f3.z, wc[14], acc); acc = fmaf(f3.w, wc[15], acc);
          float old = tm[q];
          float m = (old * 0.2f) * ((old > 0.5f) ? 0.0f : 1.0f) + acc;
          tm[q] = m;
          u64 wd = __ballot(m > 0.5f);
          if (lane == 0) spk[s * Tc + i] = wd;
        }
      }
      __syncthreads();
    }
  }

  // ============ Phase B2: temporal fc binary GEMM + h-LIF + combine ============
  {
    const int iBase = ih * 163, iN = ih ? 162 : 163;
    const float* wq0 = w2T + (size_t)(jg * 5 + 0) * (Tc * COc) + iBase * COc + lane;
    const float* wq1 = w2T + (size_t)(jg * 5 + 1) * (Tc * COc) + iBase * COc + lane;
    const float* wq2 = w2T + (size_t)(jg * 5 + 2) * (Tc * COc) + iBase * COc + lane;
    const float* wq3 = w2T + (size_t)(jg * 5 + 3) * (Tc * COc) + iBase * COc + lane;
    const float* wq4 = w2T + (size_t)(jg * 5 + 4) * (Tc * COc) + iBase * COc + lane;
    const float ba = tf1b[ja], bb = tf1b[jb];
    const float bc2 = (wv < 4) ? tf1b[jc] : 0.0f;
    float hma = 0, hsa = 0, hmb = 0, hsb = 0, hmc = 0, hsc = 0;

#pragma unroll 1
    for (int chn = 0; chn < 3; ++chn) {
      const int s0 = chn * 13;
      float ya[13][5];
#pragma unroll
      for (int ds = 0; ds < 13; ++ds)
#pragma unroll
        for (int jj = 0; jj < 5; ++jj) ya[ds][jj] = 0.0f;

#pragma unroll 1
      for (int ii = 0; ii < iN; ++ii) {
        const int i = iBase + ii;
        float w0 = wq0[(size_t)ii * COc];
        float w1 = wq1[(size_t)ii * COc];
        float w2 = wq2[(size_t)ii * COc];
        float w3 = wq3[(size_t)ii * COc];
        float w4 = wq4[(size_t)ii * COc];
#pragma unroll
        for (int ds = 0; ds < 13; ++ds) {
          u32 wrd = ((const u32*)spk)[((s0 + ds) * Tc + i) * 2 + lhalf];
          float g = (float)((wrd >> lbit) & 1u);
          ya[ds][0] = fmaf(g, w0, ya[ds][0]);
          ya[ds][1] = fmaf(g, w1, ya[ds][1]);
          ya[ds][2] = fmaf(g, w2, ya[ds][2]);
          ya[ds][3] = fmaf(g, w3, ya[ds][3]);
          ya[ds][4] = fmaf(g, w4, ya[ds][4]);
        }
      }
#pragma unroll
      for (int off = 32; off >= 1; off >>= 1)
#pragma unroll
        for (int ds = 0; ds < 13; ++ds)
#pragma unroll
          for (int jj = 0; jj < 5; ++jj)
            ya[ds][jj] += __shfl_xor(ya[ds][jj], off, 64);
      if (lane == 0) {
#pragma unroll
        for (int ds = 0; ds < 13; ++ds)
#pragma unroll
          for (int jj = 0; jj < 5; ++jj)
            partials[(jg * 2 + ih) * 65 + ds * 5 + jj] = ya[ds][jj];
      }
      __syncthreads();
#pragma unroll
      for (int ds = 0; ds < 13; ++ds) {
        float y0 = partials[(jag * 2 + 0) * 65 + ds * 5 + jaj]
                 + partials[(jag * 2 + 1) * 65 + ds * 5 + jaj] + ba;
        hma = (hma * 0.2f) * ((hma > 0.5f) ? 0.0f : 1.0f) + y0;
        hsa += (hma > 0.5f) ? 1.0f : 0.0f;
        float y1 = partials[(jbg * 2 + 0) * 65 + ds * 5 + jbj]
                 + partials[(jbg * 2 + 1) * 65 + ds * 5 + jbj] + bb;
        hmb = (hmb * 0.2f) * ((hmb > 0.5f) ? 0.0f : 1.0f) + y1;
        hsb += (hmb > 0.5f) ? 1.0f : 0.0f;
        if (wv < 4) {
          float y2 = partials[(jcg * 2 + 0) * 65 + ds * 5 + jcj]
                   + partials[(jcg * 2 + 1) * 65 + ds * 5 + jcj] + bc2;
          hmc = (hmc * 0.2f) * ((hmc > 0.5f) ? 0.0f : 1.0f) + y2;
          hsc += (hmc > 0.5f) ? 1.0f : 0.0f;
        }
      }
      __syncthreads();
    }
    if (lane == 0) {
      out[b * NCc + ja] = (outS_l[ja] + hsa / (float)NSc) * 0.5f;
      out[b * NCc + jb] = (outS_l[jb] + hsb / (float)NSc) * 0.5f;
      if (wv < 4)
        out[b * NCc + jc] = (outS_l[jc] + hsc / (float)NSc) * 0.5f;
    }
  }
}

extern "C" void kernel_launch(void* const* d_in, const int* in_sizes, int n_in,
                              void* d_out, int out_size, void* d_ws, size_t ws_size,
                              hipStream_t stream) {
  const float* data = (const float*)d_in[0];
  const int*   eiS  = (const int*)d_in[1];
  const int*   eiT  = (const int*)d_in[2];
  const float* c1w  = (const float*)d_in[3];
  const float* c1b  = (const float*)d_in[4];
  const float* c2w  = (const float*)d_in[5];
  const float* c2b  = (const float*)d_in[6];
  const float* f1w  = (const float*)d_in[7];
  const float* f1b  = (const float*)d_in[8];
  const float* tf1w = (const float*)d_in[9];
  const float* tf1b = (const float*)d_in[10];
  float* out = (float*)d_out;
  int* wsI = (int*)d_ws;
  float* wsF = (float*)d_ws;

  prep_graph<<<2, 256, 0, stream>>>(eiS, eiT, wsI, wsF);
  prep_w<<<(NCc * Tc * COc + 255) / 256, 256, 0, stream>>>(f1w, wsF + WS_W1T,
                                                           tf1w, wsF + WS_W2T);
  lif_fused<<<Bc, 512, 0, stream>>>(data,
                                    wsI + WS_ROFF_S, (const int2*)(wsI + WS_EDGE_S),
                                    wsI + WS_ROFF_T, (const int2*)(wsI + WS_EDGE_T),
                                    c1w, c1b, c2w, c2b,
                                    wsF + WS_W1T, f1b, wsF + WS_W2T, tf1b,
                                    out);
}